// Round 21
// baseline (181.686 us; speedup 1.0000x reference)
//
#include <hip/hip_runtime.h>
#include <hip/hip_bf16.h>

#define D 128
#define NH 256
#define K1 384
#define BM 64
#define NTILES 5000
#define NBLK 256
#define NNODES 10000

typedef __attribute__((ext_vector_type(8))) short bf16x8;
typedef __attribute__((ext_vector_type(4))) float f32x4;

__device__ __forceinline__ unsigned short f2b(float f) {
  unsigned int u = __builtin_bit_cast(unsigned int, f);
  u += 0x7fffu + ((u >> 16) & 1u);   // round-to-nearest-even
  return (unsigned short)(u >> 16);
}
__device__ __forceinline__ unsigned pk2(float a, float b) {
  return (unsigned)f2b(a) | ((unsigned)f2b(b) << 16);
}
__device__ __forceinline__ uint4 pack8(float4 a, float4 b) {
  uint4 r;
  r.x = pk2(a.x, a.y); r.y = pk2(a.z, a.w);
  r.z = pk2(b.x, b.y); r.w = pk2(b.z, b.w);
  return r;
}
// async global->LDS DMA: per-lane global src, wave-uniform LDS base + lane*16
__device__ __forceinline__ void gload16(const void* g, void* l) {
  __builtin_amdgcn_global_load_lds(
      (const __attribute__((address_space(1))) void*)g,
      (__attribute__((address_space(3))) void*)l, 16, 0, 0);
}

// Merged prep (one launch, r20-verified):
//  b 0..1249   : nodes fp32 -> bf16 table
//  b 1250..1297: pack W1 rows [0:384) into MFMA-fragment order
//  b 1298..1313: pack W2 (same frag order)
//  b 1314      : cvec[n] = b1[n] + sum_k globals[k]*W1[384+k][n]
__global__ void prep_kernel(const float* __restrict__ nodes,
                            const float* __restrict__ W1,
                            const float* __restrict__ W2,
                            const float* __restrict__ b1,
                            const float* __restrict__ g,
                            ushort* __restrict__ nodes_b,
                            ushort* __restrict__ W1p,
                            ushort* __restrict__ W2p,
                            float* __restrict__ cvec) {
  const int b = blockIdx.x;
  const int tid = threadIdx.x;
  if (b < 1250) {
    int i = (b * 256 + tid) * 4;
    float4 v = *(const float4*)(nodes + i);
    ushort4 o;
    o.x = f2b(v.x); o.y = f2b(v.y); o.z = f2b(v.z); o.w = f2b(v.w);
    *(ushort4*)(nodes_b + i) = o;
    return;
  }
  if (b < 1298) {
    int c = (b - 1250) * 256 + tid;   // 12288 chunks
    int nt = c / (12 * 64);
    int rem = c % (12 * 64);
    int ks = rem >> 6;
    int l = rem & 63;
    int col = nt * 16 + (l & 15);
    int k0 = ks * 32 + (l >> 4) * 8;
    ushort* dst = W1p + (size_t)c * 8;
    #pragma unroll
    for (int j = 0; j < 8; ++j)
      dst[j] = f2b(W1[(size_t)(k0 + j) * NH + col]);
    return;
  }
  if (b < 1314) {
    int c = (b - 1298) * 256 + tid;   // 4096 chunks
    int nt2 = c / (8 * 64);
    int rem = c % (8 * 64);
    int ks = rem >> 6;
    int l = rem & 63;
    int col = nt2 * 16 + (l & 15);
    int k0 = ks * 32 + (l >> 4) * 8;
    ushort* dst = W2p + (size_t)c * 8;
    #pragma unroll
    for (int j = 0; j < 8; ++j)
      dst[j] = f2b(W2[(size_t)(k0 + j) * D + col]);
    return;
  }
  {
    int n = tid;  // 256
    float acc = b1[n];
    for (int k = 0; k < D; ++k)
      acc += g[k] * W1[(size_t)(K1 + k) * NH + n];
    cvec[n] = acc;
  }
}

// Persistent pipelined kernel (r20 champion), GEMM2 re-split 2x4:
// each wave reads only 32 H-rows (halves GEMM2 LDS traffic); W2 panels
// read by 2 waves each (128 KB/tile L2 stream, trivial).
__global__ __launch_bounds__(512, 1) void fused_kernel(
    const float* __restrict__ edges,
    const ushort* __restrict__ nodes_b,
    const int* __restrict__ receivers,
    const int* __restrict__ senders,
    const ushort* __restrict__ W1p,    // packed fragments, 16nt x 12ks x 64lane x 8
    const float* __restrict__ cvec,    // [256]
    const ushort* __restrict__ W2p,    // packed fragments, 8nt x 8ks x 64lane x 8
    const float* __restrict__ b2,      // [128]
    float* __restrict__ out) {
  __shared__ char Xe[2][BM * 256];   // edges  : 2 x 16 KB, swz byte^((row&7)<<4)
  __shared__ char Xg[2][BM * 512];   // gathers: 2 x 32 KB, linear dest / pre-swz src
  __shared__ char Hs[BM * 512];      // hidden : 32 KB, swz

  const int tid = threadIdx.x;
  const int lane = tid & 63;
  const int wave = tid >> 6;
  const int lr = lane & 15;
  const int kg = lane >> 4;

  // ---- gather-staging geometry: wave stages Xg rows [8w, 8w+8), 4 instrs x 1024B
  const int l31 = lane & 31;
  const int myr = wave * 8 + (lane >> 5);        // row for instr j: myr + 2j
  const int gc2 = (l31 * 16) & 255;              // within-section byte (16B chunk)
  const int gsec = (l31 >= 16);                  // 0 = recv half, 1 = send half
  const int* __restrict__ myarr = gsec ? senders : receivers;

  // ---- edge-staging geometry: thread handles chunks tid, tid+512
  const int erow0 = tid >> 4;                    // rows erow0, erow0+32
  const int ecc = (tid & 15) * 16;               // dest byte in 256B row

  // ---- compute constants
  float cv[2];
  #pragma unroll
  for (int n = 0; n < 2; ++n) cv[n] = cvec[wave * 32 + n * 16 + lr];
  const int wm2 = wave >> 2;     // GEMM2: 2x4 wave grid (32 rows x 32 cols each)
  const int wn2 = wave & 3;
  float bias2[2];
  #pragma unroll
  for (int n = 0; n < 2; ++n) bias2[n] = b2[wn2 * 32 + n * 16 + lr];
  const ushort* w1base = W1p + (size_t)(wave * 2) * 12 * 512 + lane * 8;
  const ushort* w2base = W2p + (size_t)(wn2 * 2) * 8 * 512 + lane * 8;

  // ---- W1 fragments resident for the whole kernel (24 x bf16x8 = 96 VGPR)
  bf16x8 w1f[2][12];
  #pragma unroll
  for (int n = 0; n < 2; ++n)
    #pragma unroll
    for (int ks = 0; ks < 12; ++ks)
      w1f[n][ks] = *(const bf16x8*)(w1base + ((size_t)n * 12 + ks) * 512);

  int t = blockIdx.x;
  int idxn[4];

  // ---- prologue: stage tile t into buffer 0; preload idx for t+NBLK
  {
    const int eb = t * BM;
    int idx0[4];
    #pragma unroll
    for (int j = 0; j < 4; ++j) idx0[j] = myarr[eb + myr + 2 * j];
    #pragma unroll
    for (int j = 0; j < 4; ++j) {
      int r = myr + 2 * j;
      gload16(nodes_b + (size_t)idx0[j] * D + ((gc2 ^ ((r & 7) << 4)) >> 1),
              &Xg[0][wave * 4096 + j * 1024]);
    }
    #pragma unroll
    for (int q = 0; q < 2; ++q) {
      int row = erow0 + q * 32;
      const float* ep = edges + (size_t)(eb + row) * D + (ecc >> 1);
      float4 u0 = *(const float4*)ep;
      float4 u1 = *(const float4*)(ep + 4);
      *(uint4*)(&Xe[0][row * 256 + (ecc ^ ((row & 7) << 4))]) = pack8(u0, u1);
    }
    const int tn0 = (t + NBLK < NTILES) ? t + NBLK : t;
    #pragma unroll
    for (int j = 0; j < 4; ++j) idxn[j] = myarr[tn0 * BM + myr + 2 * j];
    __syncthreads();   // drains gload_lds (vmcnt 0) + makes Xe visible
  }

  int cur = 0;
  for (; t < NTILES; t += NBLK) {
    const int eb = t * BM;
    const int tn = (t + NBLK < NTILES) ? t + NBLK : t;
    const int t2 = (t + 2 * NBLK < NTILES) ? t + 2 * NBLK : tn;
    const int nxt = cur ^ 1;

    // 1. async gathers (tile tn) -> Xg[nxt]  (no registers held)
    #pragma unroll
    for (int j = 0; j < 4; ++j) {
      int r = myr + 2 * j;
      gload16(nodes_b + (size_t)idxn[j] * D + ((gc2 ^ ((r & 7) << 4)) >> 1),
              &Xg[nxt][wave * 4096 + j * 1024]);
    }
    // 2. edge loads (tile tn) into regs (16 VGPR, written to LDS post-GEMM2)
    float4 ev[4];
    #pragma unroll
    for (int q = 0; q < 2; ++q) {
      int row = erow0 + q * 32;
      const float* ep = edges + (size_t)(tn * BM + row) * D + (ecc >> 1);
      ev[2 * q]     = *(const float4*)ep;
      ev[2 * q + 1] = *(const float4*)(ep + 4);
    }
    // 3. idx prefetch for t+2
    int idx2[4];
    #pragma unroll
    for (int j = 0; j < 4; ++j) idx2[j] = myarr[t2 * BM + myr + 2 * j];

    // 4. GEMM1 on buffers[cur]: [64x384] @ [384x32-per-wave],
    //    A from LDS, B from RESIDENT REGISTERS (no vmcnt in loop)
    f32x4 acc[4][2] = {};
    #pragma unroll
    for (int ks = 0; ks < 12; ++ks) {
      const int k0 = ks * 32 + kg * 8;
      bf16x8 a[4];
      #pragma unroll
      for (int m = 0; m < 4; ++m) {
        int row = m * 16 + lr;
        int swz = (row & 7) << 4;
        const char* ap;
        if (ks < 4)       ap = &Xe[cur][row * 256 + ((k0 * 2) ^ swz)];
        else if (ks < 8)  ap = &Xg[cur][row * 512 + (((k0 - 128) * 2) ^ swz)];
        else              ap = &Xg[cur][row * 512 + 256 + (((k0 - 256) * 2) ^ swz)];
        a[m] = *(const bf16x8*)ap;
      }
      #pragma unroll
      for (int m = 0; m < 4; ++m)
        #pragma unroll
        for (int n = 0; n < 2; ++n)
          acc[m][n] = __builtin_amdgcn_mfma_f32_16x16x32_bf16(a[m], w1f[n][ks], acc[m][n], 0, 0, 0);
    }

    // prefetch first W2 fragments (no Hs dependency)
    bf16x8 b2b[2][2];
    #pragma unroll
    for (int n = 0; n < 2; ++n)
      b2b[0][n] = *(const bf16x8*)(w2base + (size_t)n * 8 * 512);

    // 5. epilogue 1: + cvec, relu -> bf16 Hs
    #pragma unroll
    for (int n = 0; n < 2; ++n) {
      int col = wave * 32 + n * 16 + lr;
      #pragma unroll
      for (int m = 0; m < 4; ++m) {
        #pragma unroll
        for (int r = 0; r < 4; ++r) {
          int row = m * 16 + kg * 4 + r;
          float v = acc[m][n][r] + cv[n];
          v = v > 0.f ? v : 0.f;
          *(ushort*)(&Hs[row * 512 + ((col * 2) ^ ((row & 7) << 4))]) = f2b(v);
        }
      }
    }

    // 6. barrier (staging for tn completes here, hidden under GEMM1)
    __syncthreads();

    // 7. GEMM2: [64x256] @ [256x128], 2x4 wave grid (r3-verified block):
    //    each wave reads only its 32 H-rows (halved LDS traffic)
    f32x4 acc2[2][2] = {};
    #pragma unroll
    for (int ks = 0; ks < 8; ++ks) {
      const int c2 = ks & 1, nx2 = c2 ^ 1;
      if (ks < 7) {
        #pragma unroll
        for (int n = 0; n < 2; ++n)
          b2b[nx2][n] = *(const bf16x8*)(w2base + (size_t)n * 8 * 512 + (ks + 1) * 512);
      }
      const int k0 = ks * 32 + kg * 8;
      bf16x8 a2[2];
      #pragma unroll
      for (int m = 0; m < 2; ++m) {
        int row = wm2 * 32 + m * 16 + lr;
        a2[m] = *(const bf16x8*)(&Hs[row * 512 + ((k0 * 2) ^ ((row & 7) << 4))]);
      }
      #pragma unroll
      for (int m = 0; m < 2; ++m)
        #pragma unroll
        for (int n = 0; n < 2; ++n)
          acc2[m][n] = __builtin_amdgcn_mfma_f32_16x16x32_bf16(a2[m], b2b[c2][n], acc2[m][n], 0, 0, 0);
    }

    // epilogue 2: + b2, store fp32 (wave's 32x32 tile)
    #pragma unroll
    for (int n = 0; n < 2; ++n) {
      int col = wn2 * 32 + n * 16 + lr;
      #pragma unroll
      for (int m = 0; m < 2; ++m) {
        #pragma unroll
        for (int r = 0; r < 4; ++r) {
          int row = wm2 * 32 + m * 16 + kg * 4 + r;
          out[(size_t)(eb + row) * D + col] = acc2[m][n][r] + bias2[n];
        }
      }
    }

    // 8. convert + write staged edges -> Xe[nxt]
    #pragma unroll
    for (int q = 0; q < 2; ++q) {
      int row = erow0 + q * 32;
      *(uint4*)(&Xe[nxt][row * 256 + (ecc ^ ((row & 7) << 4))]) =
          pack8(ev[2 * q], ev[2 * q + 1]);
    }

    // 9. rotate idx pipeline
    #pragma unroll
    for (int j = 0; j < 4; ++j) idxn[j] = idx2[j];

    // 10. tile boundary
    __syncthreads();
    cur = nxt;
  }
}

extern "C" void kernel_launch(void* const* d_in, const int* in_sizes, int n_in,
                              void* d_out, int out_size, void* d_ws, size_t ws_size,
                              hipStream_t stream) {
  const float* edges     = (const float*)d_in[0];
  const float* nodes     = (const float*)d_in[1];
  const float* globals_  = (const float*)d_in[2];
  const int*   receivers = (const int*)d_in[3];
  const int*   senders   = (const int*)d_in[4];
  const float* W1        = (const float*)d_in[5];
  const float* b1        = (const float*)d_in[6];
  const float* W2        = (const float*)d_in[7];
  const float* b2        = (const float*)d_in[8];
  float* out = (float*)d_out;

  char* ws = (char*)d_ws;
  ushort* nodes_b = (ushort*)ws;                                // 2,560,000 B
  ushort* W1p     = (ushort*)(ws + 2560000);                    //   196,608 B
  ushort* W2p     = (ushort*)(ws + 2560000 + 196608);           //    65,536 B
  float*  cvec    = (float*)(ws + 2560000 + 196608 + 65536);    //     1,024 B

  hipLaunchKernelGGL(prep_kernel, dim3(1315), dim3(256), 0, stream,
                     nodes, W1, W2, b1, globals_, nodes_b, W1p, W2p, cvec);
  hipLaunchKernelGGL(fused_kernel, dim3(NBLK), dim3(512), 0, stream,
                     edges, nodes_b, receivers, senders, W1p, cvec, W2p, b2, out);
}

// Round 22
// 129.050 us; speedup vs baseline: 1.4079x; 1.4079x over previous
//
#include <hip/hip_runtime.h>
#include <hip/hip_bf16.h>

#define D 128
#define NH 256
#define K1 384
#define BM 64
#define NTILES 5000
#define NBLK 256
#define NNODES 10000

typedef __attribute__((ext_vector_type(8))) short bf16x8;
typedef __attribute__((ext_vector_type(4))) float f32x4;

__device__ __forceinline__ unsigned short f2b(float f) {
  unsigned int u = __builtin_bit_cast(unsigned int, f);
  u += 0x7fffu + ((u >> 16) & 1u);   // round-to-nearest-even
  return (unsigned short)(u >> 16);
}
__device__ __forceinline__ unsigned pk2(float a, float b) {
  return (unsigned)f2b(a) | ((unsigned)f2b(b) << 16);
}
__device__ __forceinline__ uint4 pack8(float4 a, float4 b) {
  uint4 r;
  r.x = pk2(a.x, a.y); r.y = pk2(a.z, a.w);
  r.z = pk2(b.x, b.y); r.w = pk2(b.z, b.w);
  return r;
}
// async global->LDS DMA: per-lane global src, wave-uniform LDS base + lane*16
__device__ __forceinline__ void gload16(const void* g, void* l) {
  __builtin_amdgcn_global_load_lds(
      (const __attribute__((address_space(1))) void*)g,
      (__attribute__((address_space(3))) void*)l, 16, 0, 0);
}

// Merged prep (one launch, r20-verified):
//  b 0..1249   : nodes fp32 -> bf16 table
//  b 1250..1297: pack W1 rows [0:384) into MFMA-fragment order
//  b 1298..1313: pack W2 (same frag order)
//  b 1314      : cvec[n] = b1[n] + sum_k globals[k]*W1[384+k][n]
__global__ void prep_kernel(const float* __restrict__ nodes,
                            const float* __restrict__ W1,
                            const float* __restrict__ W2,
                            const float* __restrict__ b1,
                            const float* __restrict__ g,
                            ushort* __restrict__ nodes_b,
                            ushort* __restrict__ W1p,
                            ushort* __restrict__ W2p,
                            float* __restrict__ cvec) {
  const int b = blockIdx.x;
  const int tid = threadIdx.x;
  if (b < 1250) {
    int i = (b * 256 + tid) * 4;
    float4 v = *(const float4*)(nodes + i);
    ushort4 o;
    o.x = f2b(v.x); o.y = f2b(v.y); o.z = f2b(v.z); o.w = f2b(v.w);
    *(ushort4*)(nodes_b + i) = o;
    return;
  }
  if (b < 1298) {
    int c = (b - 1250) * 256 + tid;   // 12288 chunks
    int nt = c / (12 * 64);
    int rem = c % (12 * 64);
    int ks = rem >> 6;
    int l = rem & 63;
    int col = nt * 16 + (l & 15);
    int k0 = ks * 32 + (l >> 4) * 8;
    ushort* dst = W1p + (size_t)c * 8;
    #pragma unroll
    for (int j = 0; j < 8; ++j)
      dst[j] = f2b(W1[(size_t)(k0 + j) * NH + col]);
    return;
  }
  if (b < 1314) {
    int c = (b - 1298) * 256 + tid;   // 4096 chunks
    int nt2 = c / (8 * 64);
    int rem = c % (8 * 64);
    int ks = rem >> 6;
    int l = rem & 63;
    int col = nt2 * 16 + (l & 15);
    int k0 = ks * 32 + (l >> 4) * 8;
    ushort* dst = W2p + (size_t)c * 8;
    #pragma unroll
    for (int j = 0; j < 8; ++j)
      dst[j] = f2b(W2[(size_t)(k0 + j) * D + col]);
    return;
  }
  {
    int n = tid;  // 256
    float acc = b1[n];
    for (int k = 0; k < D; ++k)
      acc += g[k] * W1[(size_t)(K1 + k) * NH + n];
    cvec[n] = acc;
  }
}

// Persistent pipelined kernel (r20 champion, byte-for-byte revert):
// 256 blocks (1/CU, forced by 128 KB LDS), ~20 tiles each.
// W1 fragments register-resident (96 VGPR, loaded once; (512,1) -> 256-reg
// cap so no spill); GEMM1 pure LDS+register; W2 streamed depth-1 (1 panel
// per wave — 2 panels/wave spills, r21); GEMM2 col-split (LDS reads are
// NOT binding — r21 falsified that); staging for tile t+1 via
// global_load_lds + reg-staged edges, latency hidden under tile t.
__global__ __launch_bounds__(512, 1) void fused_kernel(
    const float* __restrict__ edges,
    const ushort* __restrict__ nodes_b,
    const int* __restrict__ receivers,
    const int* __restrict__ senders,
    const ushort* __restrict__ W1p,    // packed fragments, 16nt x 12ks x 64lane x 8
    const float* __restrict__ cvec,    // [256]
    const ushort* __restrict__ W2p,    // packed fragments, 8nt x 8ks x 64lane x 8
    const float* __restrict__ b2,      // [128]
    float* __restrict__ out) {
  __shared__ char Xe[2][BM * 256];   // edges  : 2 x 16 KB, swz byte^((row&7)<<4)
  __shared__ char Xg[2][BM * 512];   // gathers: 2 x 32 KB, linear dest / pre-swz src
  __shared__ char Hs[BM * 512];      // hidden : 32 KB, swz

  const int tid = threadIdx.x;
  const int lane = tid & 63;
  const int wave = tid >> 6;
  const int lr = lane & 15;
  const int kg = lane >> 4;

  // ---- gather-staging geometry: wave stages Xg rows [8w, 8w+8), 4 instrs x 1024B
  const int l31 = lane & 31;
  const int myr = wave * 8 + (lane >> 5);        // row for instr j: myr + 2j
  const int gc2 = (l31 * 16) & 255;              // within-section byte (16B chunk)
  const int gsec = (l31 >= 16);                  // 0 = recv half, 1 = send half
  const int* __restrict__ myarr = gsec ? senders : receivers;

  // ---- edge-staging geometry: thread handles chunks tid, tid+512
  const int erow0 = tid >> 4;                    // rows erow0, erow0+32
  const int ecc = (tid & 15) * 16;               // dest byte in 256B row

  // ---- compute constants
  float cv[2];
  #pragma unroll
  for (int n = 0; n < 2; ++n) cv[n] = cvec[wave * 32 + n * 16 + lr];
  const float bias = b2[wave * 16 + lr];
  const ushort* w1base = W1p + (size_t)(wave * 2) * 12 * 512 + lane * 8;
  const ushort* w2base = W2p + (size_t)wave * 8 * 512 + lane * 8;

  // ---- W1 fragments resident for the whole kernel (24 x bf16x8 = 96 VGPR)
  bf16x8 w1f[2][12];
  #pragma unroll
  for (int n = 0; n < 2; ++n)
    #pragma unroll
    for (int ks = 0; ks < 12; ++ks)
      w1f[n][ks] = *(const bf16x8*)(w1base + ((size_t)n * 12 + ks) * 512);

  int t = blockIdx.x;
  int idxn[4];

  // ---- prologue: stage tile t into buffer 0; preload idx for t+NBLK
  {
    const int eb = t * BM;
    int idx0[4];
    #pragma unroll
    for (int j = 0; j < 4; ++j) idx0[j] = myarr[eb + myr + 2 * j];
    #pragma unroll
    for (int j = 0; j < 4; ++j) {
      int r = myr + 2 * j;
      gload16(nodes_b + (size_t)idx0[j] * D + ((gc2 ^ ((r & 7) << 4)) >> 1),
              &Xg[0][wave * 4096 + j * 1024]);
    }
    #pragma unroll
    for (int q = 0; q < 2; ++q) {
      int row = erow0 + q * 32;
      const float* ep = edges + (size_t)(eb + row) * D + (ecc >> 1);
      float4 u0 = *(const float4*)ep;
      float4 u1 = *(const float4*)(ep + 4);
      *(uint4*)(&Xe[0][row * 256 + (ecc ^ ((row & 7) << 4))]) = pack8(u0, u1);
    }
    const int tn0 = (t + NBLK < NTILES) ? t + NBLK : t;
    #pragma unroll
    for (int j = 0; j < 4; ++j) idxn[j] = myarr[tn0 * BM + myr + 2 * j];
    __syncthreads();   // drains gload_lds (vmcnt 0) + makes Xe visible
  }

  int cur = 0;
  for (; t < NTILES; t += NBLK) {
    const int eb = t * BM;
    const int tn = (t + NBLK < NTILES) ? t + NBLK : t;
    const int t2 = (t + 2 * NBLK < NTILES) ? t + 2 * NBLK : tn;
    const int nxt = cur ^ 1;

    // 1. async gathers (tile tn) -> Xg[nxt]  (no registers held)
    #pragma unroll
    for (int j = 0; j < 4; ++j) {
      int r = myr + 2 * j;
      gload16(nodes_b + (size_t)idxn[j] * D + ((gc2 ^ ((r & 7) << 4)) >> 1),
              &Xg[nxt][wave * 4096 + j * 1024]);
    }
    // 2. edge loads (tile tn) into regs (16 VGPR, written to LDS post-GEMM2)
    float4 ev[4];
    #pragma unroll
    for (int q = 0; q < 2; ++q) {
      int row = erow0 + q * 32;
      const float* ep = edges + (size_t)(tn * BM + row) * D + (ecc >> 1);
      ev[2 * q]     = *(const float4*)ep;
      ev[2 * q + 1] = *(const float4*)(ep + 4);
    }
    // 3. idx prefetch for t+2
    int idx2[4];
    #pragma unroll
    for (int j = 0; j < 4; ++j) idx2[j] = myarr[t2 * BM + myr + 2 * j];

    // 4. GEMM1 on buffers[cur]: [64x384] @ [384x32-per-wave],
    //    A from LDS, B from RESIDENT REGISTERS (no vmcnt in loop)
    f32x4 acc[4][2] = {};
    #pragma unroll
    for (int ks = 0; ks < 12; ++ks) {
      const int k0 = ks * 32 + kg * 8;
      bf16x8 a[4];
      #pragma unroll
      for (int m = 0; m < 4; ++m) {
        int row = m * 16 + lr;
        int swz = (row & 7) << 4;
        const char* ap;
        if (ks < 4)       ap = &Xe[cur][row * 256 + ((k0 * 2) ^ swz)];
        else if (ks < 8)  ap = &Xg[cur][row * 512 + (((k0 - 128) * 2) ^ swz)];
        else              ap = &Xg[cur][row * 512 + 256 + (((k0 - 256) * 2) ^ swz)];
        a[m] = *(const bf16x8*)ap;
      }
      #pragma unroll
      for (int m = 0; m < 4; ++m)
        #pragma unroll
        for (int n = 0; n < 2; ++n)
          acc[m][n] = __builtin_amdgcn_mfma_f32_16x16x32_bf16(a[m], w1f[n][ks], acc[m][n], 0, 0, 0);
    }

    // prefetch first W2 fragment (no Hs dependency)
    bf16x8 b2b[2];
    b2b[0] = *(const bf16x8*)w2base;

    // 5. epilogue 1: + cvec, relu -> bf16 Hs
    #pragma unroll
    for (int n = 0; n < 2; ++n) {
      int col = wave * 32 + n * 16 + lr;
      #pragma unroll
      for (int m = 0; m < 4; ++m) {
        #pragma unroll
        for (int r = 0; r < 4; ++r) {
          int row = m * 16 + kg * 4 + r;
          float v = acc[m][n][r] + cv[n];
          v = v > 0.f ? v : 0.f;
          *(ushort*)(&Hs[row * 512 + ((col * 2) ^ ((row & 7) << 4))]) = f2b(v);
        }
      }
    }

    // 6. barrier (staging for tn completes here, hidden under GEMM1)
    __syncthreads();

    // 7. GEMM2: [64x256] @ [256x16-per-wave] + stores (tile t)
    f32x4 acc2[4] = {};
    #pragma unroll
    for (int ks = 0; ks < 8; ++ks) {
      const int c2 = ks & 1, nx2 = c2 ^ 1;
      if (ks < 7)
        b2b[nx2] = *(const bf16x8*)(w2base + (ks + 1) * 512);
      const int k0 = ks * 32 + kg * 8;
      bf16x8 a2[4];
      #pragma unroll
      for (int m = 0; m < 4; ++m) {
        int row = m * 16 + lr;
        a2[m] = *(const bf16x8*)(&Hs[row * 512 + ((k0 * 2) ^ ((row & 7) << 4))]);
      }
      #pragma unroll
      for (int m = 0; m < 4; ++m)
        acc2[m] = __builtin_amdgcn_mfma_f32_16x16x32_bf16(a2[m], b2b[c2], acc2[m], 0, 0, 0);
    }
    {
      int col = wave * 16 + lr;
      #pragma unroll
      for (int m = 0; m < 4; ++m) {
        #pragma unroll
        for (int r = 0; r < 4; ++r) {
          int row = m * 16 + kg * 4 + r;
          out[(size_t)(eb + row) * D + col] = acc2[m][r] + bias;
        }
      }
    }

    // 8. convert + write staged edges -> Xe[nxt]
    #pragma unroll
    for (int q = 0; q < 2; ++q) {
      int row = erow0 + q * 32;
      *(uint4*)(&Xe[nxt][row * 256 + (ecc ^ ((row & 7) << 4))]) =
          pack8(ev[2 * q], ev[2 * q + 1]);
    }

    // 9. rotate idx pipeline
    #pragma unroll
    for (int j = 0; j < 4; ++j) idxn[j] = idx2[j];

    // 10. tile boundary
    __syncthreads();
    cur = nxt;
  }
}

extern "C" void kernel_launch(void* const* d_in, const int* in_sizes, int n_in,
                              void* d_out, int out_size, void* d_ws, size_t ws_size,
                              hipStream_t stream) {
  const float* edges     = (const float*)d_in[0];
  const float* nodes     = (const float*)d_in[1];
  const float* globals_  = (const float*)d_in[2];
  const int*   receivers = (const int*)d_in[3];
  const int*   senders   = (const int*)d_in[4];
  const float* W1        = (const float*)d_in[5];
  const float* b1        = (const float*)d_in[6];
  const float* W2        = (const float*)d_in[7];
  const float* b2        = (const float*)d_in[8];
  float* out = (float*)d_out;

  char* ws = (char*)d_ws;
  ushort* nodes_b = (ushort*)ws;                                // 2,560,000 B
  ushort* W1p     = (ushort*)(ws + 2560000);                    //   196,608 B
  ushort* W2p     = (ushort*)(ws + 2560000 + 196608);           //    65,536 B
  float*  cvec    = (float*)(ws + 2560000 + 196608 + 65536);    //     1,024 B

  hipLaunchKernelGGL(prep_kernel, dim3(1315), dim3(256), 0, stream,
                     nodes, W1, W2, b1, globals_, nodes_b, W1p, W2p, cvec);
  hipLaunchKernelGGL(fused_kernel, dim3(NBLK), dim3(512), 0, stream,
                     edges, nodes_b, receivers, senders, W1p, cvec, W2p, b2, out);
}